// Round 14
// baseline (247.459 us; speedup 1.0000x reference)
//
#include <hip/hip_runtime.h>
#include <hip/hip_bf16.h>
#include <math.h>

#define NEG_SLOPE 0.2f

typedef __attribute__((ext_vector_type(8))) short short8;
typedef __attribute__((ext_vector_type(4))) float f32x4;

typedef __attribute__((address_space(1))) const void g_void;
typedef __attribute__((address_space(3))) void l_void;

__device__ __forceinline__ float lrelu(float x) { return x > 0.f ? x : NEG_SLOPE * x; }
__device__ __forceinline__ float bf2f(unsigned short u) { return __uint_as_float((unsigned)u << 16); }
__device__ __forceinline__ unsigned short f2bf(float f) {
    unsigned u = __float_as_uint(f);
    unsigned rounding = 0x7fff + ((u >> 16) & 1);
    return (unsigned short)((u + rounding) >> 16);
}

// ------------------------------------------------------------------
// prep_all: {x cvt+pad} + {W1^T cvt} + {W2^T cvt} + {count_deg}.
// ------------------------------------------------------------------
__device__ __forceinline__ void transpose_part(const float* __restrict__ in,
                                               unsigned short* __restrict__ out,
                                               int R, int Cc, int bx, int by,
                                               int tx, int ty)
{
    __shared__ float tile[32][33];
    int c0 = bx * 32, r0 = by * 32;
#pragma unroll
    for (int j = 0; j < 4; ++j)
        tile[ty + j * 8][tx] = in[(size_t)(r0 + ty + j * 8) * Cc + c0 + tx];
    __syncthreads();
#pragma unroll
    for (int j = 0; j < 4; ++j)
        out[(size_t)(c0 + ty + j * 8) * R + r0 + tx] = f2bf(tile[tx][ty + j * 8]);
}

__global__ __launch_bounds__(256) void prep_all(const float* __restrict__ x,
                                                unsigned short* __restrict__ x_bf,
                                                const float* __restrict__ W1,
                                                unsigned short* __restrict__ w1t,
                                                const float* __restrict__ W2,
                                                unsigned short* __restrict__ w2t,
                                                const int* __restrict__ ei,
                                                int* __restrict__ counts,
                                                int n_valid4, int nb_conv,
                                                int E, int E2)
{
    const int bid = blockIdx.x;
    const int tid = threadIdx.x;
    if (bid < nb_conv) {                       // x convert (+pad)
        int g = bid * 256 + tid;
        ushort4 o;
        if (g < n_valid4) {
            float4 v = *reinterpret_cast<const float4*>(x + (size_t)g * 4);
            o = make_ushort4(f2bf(v.x), f2bf(v.y), f2bf(v.z), f2bf(v.w));
        } else {
            o = make_ushort4(0, 0, 0, 0);
        }
        *reinterpret_cast<ushort4*>(x_bf + (size_t)g * 4) = o;
    } else if (bid < nb_conv + 128) {          // W1: [128][1024] -> [1024][128]
        int b = bid - nb_conv;
        transpose_part(W1, w1t, 128, 1024, b & 31, b >> 5, tid & 31, tid >> 5);
    } else if (bid < nb_conv + 128 + 256) {    // W2: [1024][256] -> [256][1024]
        int b = bid - nb_conv - 128;
        transpose_part(W2, w2t, 1024, 256, b & 7, b >> 3, tid & 31, tid >> 5);
    } else {                                   // count_deg
        int e = (bid - nb_conv - 384) * 256 + tid;
        if (e < E2) {
            int dd = (e < E) ? ei[E + e] : (e - E);
            atomicAdd(&counts[dd], 1);
        }
    }
}

// ------------------------------------------------------------------
// scan_watt: block 0 (1024 thr) = full exclusive scan of counts -> offs;
// blocks 1..8 (first 256 thr) = watt[sd][h][k] = sum_c W1[k,h*256+c]*att[c].
// ------------------------------------------------------------------
__global__ __launch_bounds__(1024) void scan_watt(const int* __restrict__ counts,
                                                  int* __restrict__ offs, int n,
                                                  const unsigned short* __restrict__ w1t,
                                                  const float* __restrict__ as1,
                                                  const float* __restrict__ ad1,
                                                  float* __restrict__ watt)
{
    if (blockIdx.x == 0) {                     // single-block scan, 10 elems/thread
        const int t = threadIdx.x;
        const int base = t * 10;
        int v[10];
        int s = 0;
#pragma unroll
        for (int k = 0; k < 10; ++k) {
            int idx = base + k;
            v[k] = (idx < n) ? counts[idx] : 0;
            s += v[k];
        }
        __shared__ int sh[1024];
        sh[t] = s;
        __syncthreads();
        for (int off = 1; off < 1024; off <<= 1) {
            int tmp = (t >= off) ? sh[t - off] : 0;
            __syncthreads();
            sh[t] += tmp;
            __syncthreads();
        }
        int run = sh[t] - s;                   // exclusive prefix
#pragma unroll
        for (int k = 0; k < 10; ++k) {
            int idx = base + k;
            if (idx < n) offs[idx] = run;
            run += v[k];
        }
        if (t == 1023) offs[n] = run;
    } else if (threadIdx.x < 256) {            // watt blocks
        const int b = blockIdx.x - 1;          // 0..7
        const int h = b >> 1, sd = b & 1;
        const float* att = (sd ? ad1 : as1) + h * 256;
        const int k = threadIdx.x & 127;
        const int chalf = threadIdx.x >> 7;
        float s = 0.f;
#pragma unroll 8
        for (int c = chalf * 128; c < chalf * 128 + 128; ++c)
            s = fmaf(bf2f(w1t[(size_t)(h * 256 + c) * 128 + k]), att[c], s);
        __shared__ float shf[256];
        shf[threadIdx.x] = s;
        __syncthreads();
        if (chalf == 0) watt[sd * 512 + h * 128 + k] = s + shf[128 + k];
    }
}

// ------------------------------------------------------------------
// scatter_score: blocks [0, nbE) = CSR scatter; rest = score1 (4 nodes/blk).
// ------------------------------------------------------------------
__global__ __launch_bounds__(256) void scatter_score(const int* __restrict__ ei, int E, int E2,
                                                     const int* __restrict__ offsets,
                                                     int* __restrict__ cursor,
                                                     int* __restrict__ csr_src, int nbE,
                                                     const unsigned short* __restrict__ x_bf,
                                                     const float* __restrict__ watt,
                                                     float* __restrict__ a_s,
                                                     float* __restrict__ a_d, int N)
{
    const int tid = threadIdx.x;
    if ((int)blockIdx.x < nbE) {
        int e = blockIdx.x * 256 + tid;
        if (e >= E2) return;
        int s, dd;
        if (e < E) { s = ei[e]; dd = ei[E + e]; }
        else       { s = e - E; dd = e - E; }
        int pos = offsets[dd] + atomicAdd(&cursor[dd], 1);
        csr_src[pos] = s;
        return;
    }
    const int n = (blockIdx.x - nbE) * 4 + (tid >> 6);
    const int lane = tid & 63;
    if (n >= N) return;
    unsigned u = *reinterpret_cast<const unsigned*>(x_bf + (size_t)n * 128 + lane * 2);
    float x0 = bf2f((unsigned short)(u & 0xffff)), x1 = bf2f((unsigned short)(u >> 16));
    float s[4], d[4];
#pragma unroll
    for (int h = 0; h < 4; ++h) {
        float2 ws = *reinterpret_cast<const float2*>(watt + h * 128 + lane * 2);
        float2 wd = *reinterpret_cast<const float2*>(watt + 512 + h * 128 + lane * 2);
        s[h] = x0 * ws.x + x1 * ws.y;
        d[h] = x0 * wd.x + x1 * wd.y;
    }
#pragma unroll
    for (int o = 32; o > 0; o >>= 1) {
#pragma unroll
        for (int h = 0; h < 4; ++h) {
            s[h] += __shfl_xor(s[h], o);
            d[h] += __shfl_xor(d[h], o);
        }
    }
    if (lane == 0) {
        *reinterpret_cast<float4*>(a_s + (size_t)n * 4) = make_float4(s[0], s[1], s[2], s[3]);
        *reinterpret_cast<float4*>(a_d + (size_t)n * 4) = make_float4(d[0], d[1], d[2], d[3]);
    }
}

// ------------------------------------------------------------------
// Generic bf16 MFMA GEMM, 128x128 tile (z-batch + bias/relu). BK=64.
// ------------------------------------------------------------------
__global__ __launch_bounds__(256) void gemm_bf16(const unsigned short* __restrict__ A, int lda,
                                                 size_t strideAz,
                                                 const unsigned short* __restrict__ Bt, int ldb,
                                                 size_t strideBz,
                                                 unsigned short* __restrict__ C, int ldc, int colz,
                                                 const float* __restrict__ bias, int relu,
                                                 int K)
{
    __shared__ unsigned short sA[128 * 64];
    __shared__ unsigned short sB[128 * 64];
    const int zb = blockIdx.z;
    A += (size_t)zb * strideAz;
    Bt += (size_t)zb * strideBz;
    const int ccol0 = zb * colz;
    const int tid = threadIdx.x;
    const int lane = tid & 63;
    const int w = tid >> 6;
    const int wr = w >> 1, wc = w & 1;
    const int m0 = blockIdx.y * 128;
    const int n0 = blockIdx.x * 128;

    f32x4 acc[4][4];
#pragma unroll
    for (int i = 0; i < 4; ++i)
#pragma unroll
        for (int j = 0; j < 4; ++j) acc[i][j] = (f32x4){0.f, 0.f, 0.f, 0.f};

    const int lrow = lane >> 3;
    const int lchunk = (lane & 7) ^ lrow;

    for (int k0 = 0; k0 < K; k0 += 64) {
#pragma unroll
        for (int i = 0; i < 4; ++i) {
            int r0 = (w * 4 + i) * 8;
            const unsigned short* g = A + (size_t)(m0 + r0 + lrow) * lda + k0 + lchunk * 8;
            __builtin_amdgcn_global_load_lds((g_void*)g, (l_void*)((char*)sA + r0 * 128), 16, 0, 0);
        }
#pragma unroll
        for (int i = 0; i < 4; ++i) {
            int r0 = (w * 4 + i) * 8;
            const unsigned short* g = Bt + (size_t)(n0 + r0 + lrow) * ldb + k0 + lchunk * 8;
            __builtin_amdgcn_global_load_lds((g_void*)g, (l_void*)((char*)sB + r0 * 128), 16, 0, 0);
        }
        __syncthreads();
#pragma unroll
        for (int kk = 0; kk < 2; ++kk) {
            short8 a[4], b[4];
#pragma unroll
            for (int i = 0; i < 4; ++i) {
                int r = wr * 64 + i * 16 + (lane & 15);
                int sw = (kk * 4 + (lane >> 4)) ^ (r & 7);
                a[i] = *reinterpret_cast<const short8*>(&sA[r * 64 + sw * 8]);
            }
#pragma unroll
            for (int j = 0; j < 4; ++j) {
                int r = wc * 64 + j * 16 + (lane & 15);
                int sw = (kk * 4 + (lane >> 4)) ^ (r & 7);
                b[j] = *reinterpret_cast<const short8*>(&sB[r * 64 + sw * 8]);
            }
#pragma unroll
            for (int i = 0; i < 4; ++i)
#pragma unroll
                for (int j = 0; j < 4; ++j)
                    acc[i][j] = __builtin_amdgcn_mfma_f32_16x16x32_bf16(a[i], b[j], acc[i][j], 0, 0, 0);
        }
        __syncthreads();
    }

#pragma unroll
    for (int i = 0; i < 4; ++i) {
        int row_b = m0 + wr * 64 + i * 16 + (lane >> 4) * 4;
#pragma unroll
        for (int j = 0; j < 4; ++j) {
            int col = n0 + wc * 64 + j * 16 + (lane & 15);
            float bv = bias ? bias[ccol0 + col] : 0.f;
#pragma unroll
            for (int r = 0; r < 4; ++r) {
                float v = acc[i][j][r] + bv;
                if (relu) v = fmaxf(v, 0.f);
                C[(size_t)(row_b + r) * ldc + ccol0 + col] = f2bf(v);
            }
        }
    }
}

// ------------------------------------------------------------------
// bf16 MFMA GEMM, 64x64 tile, BK=64 (632 blocks for M=10112,N=256),
// with fused layer-2 attn-score epilogue (atomicAdd into a_s2/a_d2).
// 4 waves; wave w owns rows w*16..w*16+15, all 64 cols: acc[4] f32x4.
// ------------------------------------------------------------------
__global__ __launch_bounds__(256) void gemm_n64(const unsigned short* __restrict__ A, int lda,
                                                const unsigned short* __restrict__ Bt, int ldb,
                                                unsigned short* __restrict__ C, int ldc,
                                                int K,
                                                const float* __restrict__ att_s,
                                                const float* __restrict__ att_d,
                                                float* __restrict__ a_s2,
                                                float* __restrict__ a_d2)
{
    __shared__ unsigned short sA[64 * 64];
    __shared__ unsigned short sB[64 * 64];
    const int tid = threadIdx.x;
    const int lane = tid & 63;
    const int w = tid >> 6;
    const int m0 = blockIdx.y * 64;
    const int n0 = blockIdx.x * 64;

    f32x4 acc[4];
#pragma unroll
    for (int j = 0; j < 4; ++j) acc[j] = (f32x4){0.f, 0.f, 0.f, 0.f};

    const int lrow = lane >> 3;
    const int lchunk = (lane & 7) ^ lrow;

    for (int k0 = 0; k0 < K; k0 += 64) {
#pragma unroll
        for (int i = 0; i < 2; ++i) {
            int r0 = (w * 2 + i) * 8;
            const unsigned short* g = A + (size_t)(m0 + r0 + lrow) * lda + k0 + lchunk * 8;
            __builtin_amdgcn_global_load_lds((g_void*)g, (l_void*)((char*)sA + r0 * 128), 16, 0, 0);
        }
#pragma unroll
        for (int i = 0; i < 2; ++i) {
            int r0 = (w * 2 + i) * 8;
            const unsigned short* g = Bt + (size_t)(n0 + r0 + lrow) * ldb + k0 + lchunk * 8;
            __builtin_amdgcn_global_load_lds((g_void*)g, (l_void*)((char*)sB + r0 * 128), 16, 0, 0);
        }
        __syncthreads();
#pragma unroll
        for (int kk = 0; kk < 2; ++kk) {
            short8 a, b[4];
            {
                int r = w * 16 + (lane & 15);
                int sw = (kk * 4 + (lane >> 4)) ^ (r & 7);
                a = *reinterpret_cast<const short8*>(&sA[r * 64 + sw * 8]);
            }
#pragma unroll
            for (int j = 0; j < 4; ++j) {
                int r = j * 16 + (lane & 15);
                int sw = (kk * 4 + (lane >> 4)) ^ (r & 7);
                b[j] = *reinterpret_cast<const short8*>(&sB[r * 64 + sw * 8]);
            }
#pragma unroll
            for (int j = 0; j < 4; ++j)
                acc[j] = __builtin_amdgcn_mfma_f32_16x16x32_bf16(a, b[j], acc[j], 0, 0, 0);
        }
        __syncthreads();
    }

    const int row_b = m0 + w * 16 + (lane >> 4) * 4;
#pragma unroll
    for (int j = 0; j < 4; ++j) {
        int col = n0 + j * 16 + (lane & 15);
#pragma unroll
        for (int r = 0; r < 4; ++r)
            C[(size_t)(row_b + r) * ldc + col] = f2bf(acc[j][r]);
    }

    // Fused attn-score partials (layer 2, H=1).
    float attS[4], attD[4];
#pragma unroll
    for (int j = 0; j < 4; ++j) {
        int col = n0 + j * 16 + (lane & 15);
        attS[j] = att_s[col];
        attD[j] = att_d[col];
    }
#pragma unroll
    for (int r = 0; r < 4; ++r) {
        float ps = 0.f, pd = 0.f;
#pragma unroll
        for (int j = 0; j < 4; ++j) {
            ps = fmaf(acc[j][r], attS[j], ps);
            pd = fmaf(acc[j][r], attD[j], pd);
        }
#pragma unroll
        for (int o = 8; o > 0; o >>= 1) {
            ps += __shfl_xor(ps, o);
            pd += __shfl_xor(pd, o);
        }
        if ((lane & 15) == 0) {
            atomicAdd(&a_s2[row_b + r], ps);
            atomicAdd(&a_d2[row_b + r], pd);
        }
    }
}

// ------------------------------------------------------------------
// zgather_f: fused softmax+gather layer 1 (no max-subtraction; scores are
// tiny, exp can't overflow). 1 wave/dst, 2 edges deep.
// ------------------------------------------------------------------
__global__ __launch_bounds__(256) void zgather_f(const unsigned short* __restrict__ x_bf,
                                                 const float* __restrict__ a_s1,
                                                 const float* __restrict__ a_d1,
                                                 const int* __restrict__ offs,
                                                 const int* __restrict__ csr,
                                                 unsigned short* __restrict__ z,
                                                 int N, int Mpad)
{
    const int wid = threadIdx.x >> 6, lane = threadIdx.x & 63;
    const int dst = blockIdx.x * 4 + wid;
    if (dst >= Mpad) return;
    const size_t zoff = (size_t)dst * 128 + lane * 2;
    if (dst >= N) {
#pragma unroll
        for (int h = 0; h < 4; ++h)
            *reinterpret_cast<unsigned*>(z + (size_t)h * Mpad * 128 + zoff) = 0u;
        return;
    }
    const int o0 = offs[dst];
    const int deg = offs[dst + 1] - o0;
    const float4 ad = *reinterpret_cast<const float4*>(a_d1 + (size_t)dst * 4);

    float acc[8];
#pragma unroll
    for (int k = 0; k < 8; ++k) acc[k] = 0.f;
    float sm0 = 0.f, sm1 = 0.f, sm2 = 0.f, sm3 = 0.f;

    int i = 0;
    for (; i + 1 < deg; i += 2) {
        int e0 = o0 + i, e1 = e0 + 1;
        int s0 = csr[e0], s1 = csr[e1];
        float4 as0 = *reinterpret_cast<const float4*>(a_s1 + (size_t)s0 * 4);
        float4 as1 = *reinterpret_cast<const float4*>(a_s1 + (size_t)s1 * 4);
        unsigned u0 = *reinterpret_cast<const unsigned*>(x_bf + (size_t)s0 * 128 + lane * 2);
        unsigned u1 = *reinterpret_cast<const unsigned*>(x_bf + (size_t)s1 * 128 + lane * 2);
        float w00 = __expf(lrelu(as0.x + ad.x)), w01 = __expf(lrelu(as0.y + ad.y));
        float w02 = __expf(lrelu(as0.z + ad.z)), w03 = __expf(lrelu(as0.w + ad.w));
        float w10 = __expf(lrelu(as1.x + ad.x)), w11 = __expf(lrelu(as1.y + ad.y));
        float w12 = __expf(lrelu(as1.z + ad.z)), w13 = __expf(lrelu(as1.w + ad.w));
        sm0 += w00 + w10; sm1 += w01 + w11; sm2 += w02 + w12; sm3 += w03 + w13;
        float x00 = bf2f((unsigned short)(u0 & 0xffff)), x01 = bf2f((unsigned short)(u0 >> 16));
        float x10 = bf2f((unsigned short)(u1 & 0xffff)), x11 = bf2f((unsigned short)(u1 >> 16));
        acc[0] = fmaf(w00, x00, acc[0]); acc[1] = fmaf(w00, x01, acc[1]);
        acc[2] = fmaf(w01, x00, acc[2]); acc[3] = fmaf(w01, x01, acc[3]);
        acc[4] = fmaf(w02, x00, acc[4]); acc[5] = fmaf(w02, x01, acc[5]);
        acc[6] = fmaf(w03, x00, acc[6]); acc[7] = fmaf(w03, x01, acc[7]);
        acc[0] = fmaf(w10, x10, acc[0]); acc[1] = fmaf(w10, x11, acc[1]);
        acc[2] = fmaf(w11, x10, acc[2]); acc[3] = fmaf(w11, x11, acc[3]);
        acc[4] = fmaf(w12, x10, acc[4]); acc[5] = fmaf(w12, x11, acc[5]);
        acc[6] = fmaf(w13, x10, acc[6]); acc[7] = fmaf(w13, x11, acc[7]);
    }
    if (i < deg) {
        int e0 = o0 + i;
        int s0 = csr[e0];
        float4 as0 = *reinterpret_cast<const float4*>(a_s1 + (size_t)s0 * 4);
        unsigned u0 = *reinterpret_cast<const unsigned*>(x_bf + (size_t)s0 * 128 + lane * 2);
        float w00 = __expf(lrelu(as0.x + ad.x)), w01 = __expf(lrelu(as0.y + ad.y));
        float w02 = __expf(lrelu(as0.z + ad.z)), w03 = __expf(lrelu(as0.w + ad.w));
        sm0 += w00; sm1 += w01; sm2 += w02; sm3 += w03;
        float x00 = bf2f((unsigned short)(u0 & 0xffff)), x01 = bf2f((unsigned short)(u0 >> 16));
        acc[0] = fmaf(w00, x00, acc[0]); acc[1] = fmaf(w00, x01, acc[1]);
        acc[2] = fmaf(w01, x00, acc[2]); acc[3] = fmaf(w01, x01, acc[3]);
        acc[4] = fmaf(w02, x00, acc[4]); acc[5] = fmaf(w02, x01, acc[5]);
        acc[6] = fmaf(w03, x00, acc[6]); acc[7] = fmaf(w03, x01, acc[7]);
    }
    float inv[4] = {1.f / sm0, 1.f / sm1, 1.f / sm2, 1.f / sm3};
#pragma unroll
    for (int h = 0; h < 4; ++h) {
        unsigned o = (unsigned)f2bf(acc[h * 2] * inv[h]) |
                     ((unsigned)f2bf(acc[h * 2 + 1] * inv[h]) << 16);
        *reinterpret_cast<unsigned*>(z + (size_t)h * Mpad * 128 + zoff) = o;
    }
}

// ------------------------------------------------------------------
// gather2_f: fused softmax+gather layer 2 (H=1), XCD-pinned 2 panels,
// + fused mean accumulation (per-block LDS reduce -> atomicAdd meanv).
// No h2 materialization. All threads execute both barriers.
// ------------------------------------------------------------------
__global__ __launch_bounds__(256) void gather2_f(const unsigned short* __restrict__ xl,
                                                 const float* __restrict__ a_s,
                                                 const float* __restrict__ a_d,
                                                 const int* __restrict__ offsets,
                                                 const int* __restrict__ csr_src,
                                                 const float* __restrict__ bias,
                                                 float* __restrict__ meanv, int N)
{
    const int panel = blockIdx.x & 1;
    const int dstq = blockIdx.x >> 1;
    const int wid = threadIdx.x >> 6;
    const int lane = threadIdx.x & 63;
    const int dst = dstq * 4 + wid;
    const bool valid = dst < N;
    const int g = lane >> 4;
    const int cb = panel * 128 + (lane & 15) * 8;

    __shared__ float psum[128];
    if (threadIdx.x < 128) psum[threadIdx.x] = 0.f;
    __syncthreads();

    float r[8];
#pragma unroll
    for (int k = 0; k < 8; ++k) r[k] = 0.f;

    if (valid) {
        const float ad = a_d[dst];
        const int o0 = offsets[dst];
        const int deg = offsets[dst + 1] - o0;

        float acc[8];
#pragma unroll
        for (int k = 0; k < 8; ++k) acc[k] = 0.f;
        float ssum = 0.f;

        int i = g;
        for (; i + 4 < deg; i += 8) {
            int e0 = o0 + i, e1 = e0 + 4;
            int s0 = csr_src[e0], s1 = csr_src[e1];
            float w0 = __expf(lrelu(a_s[s0] + ad));
            float w1 = __expf(lrelu(a_s[s1] + ad));
            ssum += w0 + w1;
            short8 v0 = *reinterpret_cast<const short8*>(xl + (size_t)s0 * 256 + cb);
            short8 v1 = *reinterpret_cast<const short8*>(xl + (size_t)s1 * 256 + cb);
#pragma unroll
            for (int k = 0; k < 8; ++k) {
                acc[k] = fmaf(w0, bf2f((unsigned short)v0[k]), acc[k]);
                acc[k] = fmaf(w1, bf2f((unsigned short)v1[k]), acc[k]);
            }
        }
        for (; i < deg; i += 4) {
            int e = o0 + i;
            int s = csr_src[e];
            float w = __expf(lrelu(a_s[s] + ad));
            ssum += w;
            short8 v = *reinterpret_cast<const short8*>(xl + (size_t)s * 256 + cb);
#pragma unroll
            for (int k = 0; k < 8; ++k)
                acc[k] = fmaf(w, bf2f((unsigned short)v[k]), acc[k]);
        }
        ssum += __shfl_xor(ssum, 16);
        ssum += __shfl_xor(ssum, 32);
#pragma unroll
        for (int k = 0; k < 8; ++k) {
            acc[k] += __shfl_xor(acc[k], 16);
            acc[k] += __shfl_xor(acc[k], 32);
        }
        if (lane < 16) {
            const float inv = 1.f / ssum;
            float4 b0 = *reinterpret_cast<const float4*>(bias + cb);
            float4 b1 = *reinterpret_cast<const float4*>(bias + cb + 4);
            r[0] = fmaxf(acc[0] * inv + b0.x, 0.f); r[1] = fmaxf(acc[1] * inv + b0.y, 0.f);
            r[2] = fmaxf(acc[2] * inv + b0.z, 0.f); r[3] = fmaxf(acc[3] * inv + b0.w, 0.f);
            r[4] = fmaxf(acc[4] * inv + b1.x, 0.f); r[5] = fmaxf(acc[5] * inv + b1.y, 0.f);
            r[6] = fmaxf(acc[6] * inv + b1.z, 0.f); r[7] = fmaxf(acc[7] * inv + b1.w, 0.f);
        }
    }

    if (valid && lane < 16) {
        const int lc = (lane & 15) * 8;
#pragma unroll
        for (int k = 0; k < 8; ++k)
            atomicAdd(&psum[lc + k], r[k]);
    }
    __syncthreads();
    if (threadIdx.x < 128)
        atomicAdd(&meanv[panel * 128 + threadIdx.x], psum[threadIdx.x]);
}

// ------------------------------------------------------------------
__global__ __launch_bounds__(64) void final_k(const float* __restrict__ meanv,
                                              const float* __restrict__ Wc,
                                              const float* __restrict__ bc,
                                              float* __restrict__ out, int N, int NCLS)
{
    int k = threadIdx.x;
    if (k >= NCLS) return;
    float invN = 1.f / (float)N;
    float s = 0.f;
    for (int c = 0; c < 256; ++c)
        s = fmaf(meanv[c] * invN, Wc[c * NCLS + k], s);
    out[k] = s + bc[k];
}

// ------------------------------------------------------------------
extern "C" void kernel_launch(void* const* d_in, const int* in_sizes, int n_in,
                              void* d_out, int out_size, void* d_ws, size_t ws_size,
                              hipStream_t stream)
{
    const float* x   = (const float*)d_in[0];
    const int*   ei  = (const int*)d_in[1];
    const float* W1  = (const float*)d_in[2];
    const float* as1 = (const float*)d_in[3];
    const float* ad1 = (const float*)d_in[4];
    const float* b1  = (const float*)d_in[5];
    const float* W2  = (const float*)d_in[6];
    const float* as2 = (const float*)d_in[7];
    const float* ad2 = (const float*)d_in[8];
    const float* b2  = (const float*)d_in[9];
    const float* Wc  = (const float*)d_in[10];
    const float* bc  = (const float*)d_in[11];
    float* out = (float*)d_out;

    const int D = 128, H = 4, C = 256, HC = 1024;
    const int N = in_sizes[0] / D;              // 10000
    const int E = in_sizes[1] / 2;              // 160000
    const int E2 = E + N;
    const int NCLS = in_sizes[11];
    const int Mpad = ((N + 127) / 128) * 128;   // 10112
    const int NB_CONV = Mpad * D / 4 / 256;     // 1264
    const int NB_E = (E2 + 255) / 256;          // 665

    char* ws = (char*)d_ws;
    size_t woff = 0;
    auto take = [&](size_t bytes) -> char* {
        char* p = ws + woff;
        woff += (bytes + 255) & ~(size_t)255;
        return p;
    };
    unsigned short* x_bf  = (unsigned short*)take((size_t)Mpad * D * 2);
    unsigned short* w1t   = (unsigned short*)take((size_t)HC * D * 2);
    unsigned short* w2t   = (unsigned short*)take((size_t)C * HC * 2);
    unsigned short* z     = (unsigned short*)take((size_t)4 * Mpad * 128 * 2);
    unsigned short* h1    = (unsigned short*)take((size_t)Mpad * HC * 2);
    unsigned short* xl2   = (unsigned short*)take((size_t)Mpad * C * 2);
    float* watt   = (float*)take(1024 * 4);
    float* a_s1   = (float*)take((size_t)N * H * 4);
    float* a_d1   = (float*)take((size_t)N * H * 4);
    int*   offs   = (int*)take((size_t)(N + 1) * 4);
    int*   csrsrc = (int*)take((size_t)E2 * 4);
    // ---- contiguous zero-init region (single memset) ----
    char* zero_base = ws + woff;
    int*   counts = (int*)take((size_t)N * 4);
    int*   cursor = (int*)take((size_t)N * 4);
    float* a_s2   = (float*)take((size_t)Mpad * 4);   // atomic targets
    float* a_d2   = (float*)take((size_t)Mpad * 4);
    float* meanv  = (float*)take(256 * 4);
    size_t zero_bytes = (size_t)((ws + woff) - zero_base);

    hipMemsetAsync(zero_base, 0, zero_bytes, stream);

    // prep + count_deg (fused)
    prep_all<<<NB_CONV + 128 + 256 + NB_E, 256, 0, stream>>>(
        x, x_bf, W1, w1t, W2, w2t, ei, counts, N * D / 4, NB_CONV, E, E2);

    // scan (block 0) + watt (blocks 1..8)
    scan_watt<<<9, 1024, 0, stream>>>(counts, offs, N, w1t, as1, ad1, watt);

    // scatter + score1 (fused)
    scatter_score<<<NB_E + (N + 3) / 4, 256, 0, stream>>>(
        ei, E, E2, offs, cursor, csrsrc, NB_E, x_bf, watt, a_s1, a_d1, N);

    // Layer 1: fused softmax-gather on x, then block-diag GEMM
    zgather_f<<<(Mpad + 3) / 4, 256, 0, stream>>>(x_bf, a_s1, a_d1, offs, csrsrc, z, N, Mpad);
    gemm_bf16<<<dim3(2, Mpad / 128, 4), 256, 0, stream>>>(
        z, 128, (size_t)Mpad * 128, w1t, 128, (size_t)256 * 128,
        h1, 1024, 256, b1, 1, 128);

    // Layer 2: GEMM (+fused attn scores) then fused softmax-gather+mean
    gemm_n64<<<dim3(C / 64, Mpad / 64), 256, 0, stream>>>(
        h1, 1024, w2t, 1024, xl2, 256, 1024, as2, ad2, a_s2, a_d2);
    gather2_f<<<((N + 3) / 4) * 2, 256, 0, stream>>>(xl2, a_s2, a_d2, offs, csrsrc, b2, meanv, N);

    // Classifier
    final_k<<<1, 64, 0, stream>>>(meanv, Wc, bc, out, N, NCLS);
}

// Round 16
// 202.626 us; speedup vs baseline: 1.2213x; 1.2213x over previous
//
#include <hip/hip_runtime.h>
#include <hip/hip_bf16.h>
#include <math.h>

#define NEG_SLOPE 0.2f

typedef __attribute__((ext_vector_type(8))) short short8;
typedef __attribute__((ext_vector_type(4))) float f32x4;

typedef __attribute__((address_space(1))) const void g_void;
typedef __attribute__((address_space(3))) void l_void;

__device__ __forceinline__ float lrelu(float x) { return x > 0.f ? x : NEG_SLOPE * x; }
__device__ __forceinline__ float bf2f(unsigned short u) { return __uint_as_float((unsigned)u << 16); }
__device__ __forceinline__ unsigned short f2bf(float f) {
    unsigned u = __float_as_uint(f);
    unsigned rounding = 0x7fff + ((u >> 16) & 1);
    return (unsigned short)((u + rounding) >> 16);
}

// ------------------------------------------------------------------
// prep_all: {x cvt+pad} + {W1^T cvt} + {W2^T cvt} + {count_deg}.
// ------------------------------------------------------------------
__device__ __forceinline__ void transpose_part(const float* __restrict__ in,
                                               unsigned short* __restrict__ out,
                                               int R, int Cc, int bx, int by,
                                               int tx, int ty)
{
    __shared__ float tile[32][33];
    int c0 = bx * 32, r0 = by * 32;
#pragma unroll
    for (int j = 0; j < 4; ++j)
        tile[ty + j * 8][tx] = in[(size_t)(r0 + ty + j * 8) * Cc + c0 + tx];
    __syncthreads();
#pragma unroll
    for (int j = 0; j < 4; ++j)
        out[(size_t)(c0 + ty + j * 8) * R + r0 + tx] = f2bf(tile[tx][ty + j * 8]);
}

__global__ __launch_bounds__(256) void prep_all(const float* __restrict__ x,
                                                unsigned short* __restrict__ x_bf,
                                                const float* __restrict__ W1,
                                                unsigned short* __restrict__ w1t,
                                                const float* __restrict__ W2,
                                                unsigned short* __restrict__ w2t,
                                                const int* __restrict__ ei,
                                                int* __restrict__ counts,
                                                int n_valid4, int nb_conv,
                                                int E, int E2)
{
    const int bid = blockIdx.x;
    const int tid = threadIdx.x;
    if (bid < nb_conv) {                       // x convert (+pad)
        int g = bid * 256 + tid;
        ushort4 o;
        if (g < n_valid4) {
            float4 v = *reinterpret_cast<const float4*>(x + (size_t)g * 4);
            o = make_ushort4(f2bf(v.x), f2bf(v.y), f2bf(v.z), f2bf(v.w));
        } else {
            o = make_ushort4(0, 0, 0, 0);
        }
        *reinterpret_cast<ushort4*>(x_bf + (size_t)g * 4) = o;
    } else if (bid < nb_conv + 128) {          // W1: [128][1024] -> [1024][128]
        int b = bid - nb_conv;
        transpose_part(W1, w1t, 128, 1024, b & 31, b >> 5, tid & 31, tid >> 5);
    } else if (bid < nb_conv + 128 + 256) {    // W2: [1024][256] -> [256][1024]
        int b = bid - nb_conv - 128;
        transpose_part(W2, w2t, 1024, 256, b & 7, b >> 3, tid & 31, tid >> 5);
    } else {                                   // count_deg
        int e = (bid - nb_conv - 384) * 256 + tid;
        if (e < E2) {
            int dd = (e < E) ? ei[E + e] : (e - E);
            atomicAdd(&counts[dd], 1);
        }
    }
}

// ------------------------------------------------------------------
// scan_watt: block 0 (1024 thr) = full exclusive scan of counts -> offs;
// blocks 1..8 (first 256 thr) = watt[sd][h][k] = sum_c W1[k,h*256+c]*att[c].
// ------------------------------------------------------------------
__global__ __launch_bounds__(1024) void scan_watt(const int* __restrict__ counts,
                                                  int* __restrict__ offs, int n,
                                                  const unsigned short* __restrict__ w1t,
                                                  const float* __restrict__ as1,
                                                  const float* __restrict__ ad1,
                                                  float* __restrict__ watt)
{
    if (blockIdx.x == 0) {                     // single-block scan, 10 elems/thread
        const int t = threadIdx.x;
        const int base = t * 10;
        int v[10];
        int s = 0;
#pragma unroll
        for (int k = 0; k < 10; ++k) {
            int idx = base + k;
            v[k] = (idx < n) ? counts[idx] : 0;
            s += v[k];
        }
        __shared__ int sh[1024];
        sh[t] = s;
        __syncthreads();
        for (int off = 1; off < 1024; off <<= 1) {
            int tmp = (t >= off) ? sh[t - off] : 0;
            __syncthreads();
            sh[t] += tmp;
            __syncthreads();
        }
        int run = sh[t] - s;                   // exclusive prefix
#pragma unroll
        for (int k = 0; k < 10; ++k) {
            int idx = base + k;
            if (idx < n) offs[idx] = run;
            run += v[k];
        }
        if (t == 1023) offs[n] = run;
    } else if (threadIdx.x < 256) {            // watt blocks
        const int b = blockIdx.x - 1;          // 0..7
        const int h = b >> 1, sd = b & 1;
        const float* att = (sd ? ad1 : as1) + h * 256;
        const int k = threadIdx.x & 127;
        const int chalf = threadIdx.x >> 7;
        float s = 0.f;
#pragma unroll 8
        for (int c = chalf * 128; c < chalf * 128 + 128; ++c)
            s = fmaf(bf2f(w1t[(size_t)(h * 256 + c) * 128 + k]), att[c], s);
        __shared__ float shf[256];
        shf[threadIdx.x] = s;
        __syncthreads();
        if (chalf == 0) watt[sd * 512 + h * 128 + k] = s + shf[128 + k];
    }
}

// ------------------------------------------------------------------
// scatter_score: blocks [0, nbE) = CSR scatter; rest = score1 (4 nodes/blk).
// ------------------------------------------------------------------
__global__ __launch_bounds__(256) void scatter_score(const int* __restrict__ ei, int E, int E2,
                                                     const int* __restrict__ offsets,
                                                     int* __restrict__ cursor,
                                                     int* __restrict__ csr_src, int nbE,
                                                     const unsigned short* __restrict__ x_bf,
                                                     const float* __restrict__ watt,
                                                     float* __restrict__ a_s,
                                                     float* __restrict__ a_d, int N)
{
    const int tid = threadIdx.x;
    if ((int)blockIdx.x < nbE) {
        int e = blockIdx.x * 256 + tid;
        if (e >= E2) return;
        int s, dd;
        if (e < E) { s = ei[e]; dd = ei[E + e]; }
        else       { s = e - E; dd = e - E; }
        int pos = offsets[dd] + atomicAdd(&cursor[dd], 1);
        csr_src[pos] = s;
        return;
    }
    const int n = (blockIdx.x - nbE) * 4 + (tid >> 6);
    const int lane = tid & 63;
    if (n >= N) return;
    unsigned u = *reinterpret_cast<const unsigned*>(x_bf + (size_t)n * 128 + lane * 2);
    float x0 = bf2f((unsigned short)(u & 0xffff)), x1 = bf2f((unsigned short)(u >> 16));
    float s[4], d[4];
#pragma unroll
    for (int h = 0; h < 4; ++h) {
        float2 ws = *reinterpret_cast<const float2*>(watt + h * 128 + lane * 2);
        float2 wd = *reinterpret_cast<const float2*>(watt + 512 + h * 128 + lane * 2);
        s[h] = x0 * ws.x + x1 * ws.y;
        d[h] = x0 * wd.x + x1 * wd.y;
    }
#pragma unroll
    for (int o = 32; o > 0; o >>= 1) {
#pragma unroll
        for (int h = 0; h < 4; ++h) {
            s[h] += __shfl_xor(s[h], o);
            d[h] += __shfl_xor(d[h], o);
        }
    }
    if (lane == 0) {
        *reinterpret_cast<float4*>(a_s + (size_t)n * 4) = make_float4(s[0], s[1], s[2], s[3]);
        *reinterpret_cast<float4*>(a_d + (size_t)n * 4) = make_float4(d[0], d[1], d[2], d[3]);
    }
}

// ------------------------------------------------------------------
// Generic bf16 MFMA GEMM, 128x128 tile (z-batch + bias/relu). BK=64.
// ------------------------------------------------------------------
__global__ __launch_bounds__(256) void gemm_bf16(const unsigned short* __restrict__ A, int lda,
                                                 size_t strideAz,
                                                 const unsigned short* __restrict__ Bt, int ldb,
                                                 size_t strideBz,
                                                 unsigned short* __restrict__ C, int ldc, int colz,
                                                 const float* __restrict__ bias, int relu,
                                                 int K)
{
    __shared__ unsigned short sA[128 * 64];
    __shared__ unsigned short sB[128 * 64];
    const int zb = blockIdx.z;
    A += (size_t)zb * strideAz;
    Bt += (size_t)zb * strideBz;
    const int ccol0 = zb * colz;
    const int tid = threadIdx.x;
    const int lane = tid & 63;
    const int w = tid >> 6;
    const int wr = w >> 1, wc = w & 1;
    const int m0 = blockIdx.y * 128;
    const int n0 = blockIdx.x * 128;

    f32x4 acc[4][4];
#pragma unroll
    for (int i = 0; i < 4; ++i)
#pragma unroll
        for (int j = 0; j < 4; ++j) acc[i][j] = (f32x4){0.f, 0.f, 0.f, 0.f};

    const int lrow = lane >> 3;
    const int lchunk = (lane & 7) ^ lrow;

    for (int k0 = 0; k0 < K; k0 += 64) {
#pragma unroll
        for (int i = 0; i < 4; ++i) {
            int r0 = (w * 4 + i) * 8;
            const unsigned short* g = A + (size_t)(m0 + r0 + lrow) * lda + k0 + lchunk * 8;
            __builtin_amdgcn_global_load_lds((g_void*)g, (l_void*)((char*)sA + r0 * 128), 16, 0, 0);
        }
#pragma unroll
        for (int i = 0; i < 4; ++i) {
            int r0 = (w * 4 + i) * 8;
            const unsigned short* g = Bt + (size_t)(n0 + r0 + lrow) * ldb + k0 + lchunk * 8;
            __builtin_amdgcn_global_load_lds((g_void*)g, (l_void*)((char*)sB + r0 * 128), 16, 0, 0);
        }
        __syncthreads();
#pragma unroll
        for (int kk = 0; kk < 2; ++kk) {
            short8 a[4], b[4];
#pragma unroll
            for (int i = 0; i < 4; ++i) {
                int r = wr * 64 + i * 16 + (lane & 15);
                int sw = (kk * 4 + (lane >> 4)) ^ (r & 7);
                a[i] = *reinterpret_cast<const short8*>(&sA[r * 64 + sw * 8]);
            }
#pragma unroll
            for (int j = 0; j < 4; ++j) {
                int r = wc * 64 + j * 16 + (lane & 15);
                int sw = (kk * 4 + (lane >> 4)) ^ (r & 7);
                b[j] = *reinterpret_cast<const short8*>(&sB[r * 64 + sw * 8]);
            }
#pragma unroll
            for (int i = 0; i < 4; ++i)
#pragma unroll
                for (int j = 0; j < 4; ++j)
                    acc[i][j] = __builtin_amdgcn_mfma_f32_16x16x32_bf16(a[i], b[j], acc[i][j], 0, 0, 0);
        }
        __syncthreads();
    }

#pragma unroll
    for (int i = 0; i < 4; ++i) {
        int row_b = m0 + wr * 64 + i * 16 + (lane >> 4) * 4;
#pragma unroll
        for (int j = 0; j < 4; ++j) {
            int col = n0 + wc * 64 + j * 16 + (lane & 15);
            float bv = bias ? bias[ccol0 + col] : 0.f;
#pragma unroll
            for (int r = 0; r < 4; ++r) {
                float v = acc[i][j][r] + bv;
                if (relu) v = fmaxf(v, 0.f);
                C[(size_t)(row_b + r) * ldc + ccol0 + col] = f2bf(v);
            }
        }
    }
}

// ------------------------------------------------------------------
// bf16 MFMA GEMM, 64x64 tile, BK=64 (632 blocks for M=10112,N=256),
// with fused layer-2 attn-score epilogue (atomicAdd into a_s2/a_d2).
// ------------------------------------------------------------------
__global__ __launch_bounds__(256) void gemm_n64(const unsigned short* __restrict__ A, int lda,
                                                const unsigned short* __restrict__ Bt, int ldb,
                                                unsigned short* __restrict__ C, int ldc,
                                                int K,
                                                const float* __restrict__ att_s,
                                                const float* __restrict__ att_d,
                                                float* __restrict__ a_s2,
                                                float* __restrict__ a_d2)
{
    __shared__ unsigned short sA[64 * 64];
    __shared__ unsigned short sB[64 * 64];
    const int tid = threadIdx.x;
    const int lane = tid & 63;
    const int w = tid >> 6;
    const int m0 = blockIdx.y * 64;
    const int n0 = blockIdx.x * 64;

    f32x4 acc[4];
#pragma unroll
    for (int j = 0; j < 4; ++j) acc[j] = (f32x4){0.f, 0.f, 0.f, 0.f};

    const int lrow = lane >> 3;
    const int lchunk = (lane & 7) ^ lrow;

    for (int k0 = 0; k0 < K; k0 += 64) {
#pragma unroll
        for (int i = 0; i < 2; ++i) {
            int r0 = (w * 2 + i) * 8;
            const unsigned short* g = A + (size_t)(m0 + r0 + lrow) * lda + k0 + lchunk * 8;
            __builtin_amdgcn_global_load_lds((g_void*)g, (l_void*)((char*)sA + r0 * 128), 16, 0, 0);
        }
#pragma unroll
        for (int i = 0; i < 2; ++i) {
            int r0 = (w * 2 + i) * 8;
            const unsigned short* g = Bt + (size_t)(n0 + r0 + lrow) * ldb + k0 + lchunk * 8;
            __builtin_amdgcn_global_load_lds((g_void*)g, (l_void*)((char*)sB + r0 * 128), 16, 0, 0);
        }
        __syncthreads();
#pragma unroll
        for (int kk = 0; kk < 2; ++kk) {
            short8 a, b[4];
            {
                int r = w * 16 + (lane & 15);
                int sw = (kk * 4 + (lane >> 4)) ^ (r & 7);
                a = *reinterpret_cast<const short8*>(&sA[r * 64 + sw * 8]);
            }
#pragma unroll
            for (int j = 0; j < 4; ++j) {
                int r = j * 16 + (lane & 15);
                int sw = (kk * 4 + (lane >> 4)) ^ (r & 7);
                b[j] = *reinterpret_cast<const short8*>(&sB[r * 64 + sw * 8]);
            }
#pragma unroll
            for (int j = 0; j < 4; ++j)
                acc[j] = __builtin_amdgcn_mfma_f32_16x16x32_bf16(a, b[j], acc[j], 0, 0, 0);
        }
        __syncthreads();
    }

    const int row_b = m0 + w * 16 + (lane >> 4) * 4;
#pragma unroll
    for (int j = 0; j < 4; ++j) {
        int col = n0 + j * 16 + (lane & 15);
#pragma unroll
        for (int r = 0; r < 4; ++r)
            C[(size_t)(row_b + r) * ldc + col] = f2bf(acc[j][r]);
    }

    // Fused attn-score partials (layer 2, H=1).
    float attS[4], attD[4];
#pragma unroll
    for (int j = 0; j < 4; ++j) {
        int col = n0 + j * 16 + (lane & 15);
        attS[j] = att_s[col];
        attD[j] = att_d[col];
    }
#pragma unroll
    for (int r = 0; r < 4; ++r) {
        float ps = 0.f, pd = 0.f;
#pragma unroll
        for (int j = 0; j < 4; ++j) {
            ps = fmaf(acc[j][r], attS[j], ps);
            pd = fmaf(acc[j][r], attD[j], pd);
        }
#pragma unroll
        for (int o = 8; o > 0; o >>= 1) {
            ps += __shfl_xor(ps, o);
            pd += __shfl_xor(pd, o);
        }
        if ((lane & 15) == 0) {
            atomicAdd(&a_s2[row_b + r], ps);
            atomicAdd(&a_d2[row_b + r], pd);
        }
    }
}

// ------------------------------------------------------------------
// zgather_f: fused softmax+gather layer 1. 1 wave/dst, 2 edges deep.
// ------------------------------------------------------------------
__global__ __launch_bounds__(256) void zgather_f(const unsigned short* __restrict__ x_bf,
                                                 const float* __restrict__ a_s1,
                                                 const float* __restrict__ a_d1,
                                                 const int* __restrict__ offs,
                                                 const int* __restrict__ csr,
                                                 unsigned short* __restrict__ z,
                                                 int N, int Mpad)
{
    const int wid = threadIdx.x >> 6, lane = threadIdx.x & 63;
    const int dst = blockIdx.x * 4 + wid;
    if (dst >= Mpad) return;
    const size_t zoff = (size_t)dst * 128 + lane * 2;
    if (dst >= N) {
#pragma unroll
        for (int h = 0; h < 4; ++h)
            *reinterpret_cast<unsigned*>(z + (size_t)h * Mpad * 128 + zoff) = 0u;
        return;
    }
    const int o0 = offs[dst];
    const int deg = offs[dst + 1] - o0;
    const float4 ad = *reinterpret_cast<const float4*>(a_d1 + (size_t)dst * 4);

    float acc[8];
#pragma unroll
    for (int k = 0; k < 8; ++k) acc[k] = 0.f;
    float sm0 = 0.f, sm1 = 0.f, sm2 = 0.f, sm3 = 0.f;

    int i = 0;
    for (; i + 1 < deg; i += 2) {
        int e0 = o0 + i, e1 = e0 + 1;
        int s0 = csr[e0], s1 = csr[e1];
        float4 as0 = *reinterpret_cast<const float4*>(a_s1 + (size_t)s0 * 4);
        float4 as1 = *reinterpret_cast<const float4*>(a_s1 + (size_t)s1 * 4);
        unsigned u0 = *reinterpret_cast<const unsigned*>(x_bf + (size_t)s0 * 128 + lane * 2);
        unsigned u1 = *reinterpret_cast<const unsigned*>(x_bf + (size_t)s1 * 128 + lane * 2);
        float w00 = __expf(lrelu(as0.x + ad.x)), w01 = __expf(lrelu(as0.y + ad.y));
        float w02 = __expf(lrelu(as0.z + ad.z)), w03 = __expf(lrelu(as0.w + ad.w));
        float w10 = __expf(lrelu(as1.x + ad.x)), w11 = __expf(lrelu(as1.y + ad.y));
        float w12 = __expf(lrelu(as1.z + ad.z)), w13 = __expf(lrelu(as1.w + ad.w));
        sm0 += w00 + w10; sm1 += w01 + w11; sm2 += w02 + w12; sm3 += w03 + w13;
        float x00 = bf2f((unsigned short)(u0 & 0xffff)), x01 = bf2f((unsigned short)(u0 >> 16));
        float x10 = bf2f((unsigned short)(u1 & 0xffff)), x11 = bf2f((unsigned short)(u1 >> 16));
        acc[0] = fmaf(w00, x00, acc[0]); acc[1] = fmaf(w00, x01, acc[1]);
        acc[2] = fmaf(w01, x00, acc[2]); acc[3] = fmaf(w01, x01, acc[3]);
        acc[4] = fmaf(w02, x00, acc[4]); acc[5] = fmaf(w02, x01, acc[5]);
        acc[6] = fmaf(w03, x00, acc[6]); acc[7] = fmaf(w03, x01, acc[7]);
        acc[0] = fmaf(w10, x10, acc[0]); acc[1] = fmaf(w10, x11, acc[1]);
        acc[2] = fmaf(w11, x10, acc[2]); acc[3] = fmaf(w11, x11, acc[3]);
        acc[4] = fmaf(w12, x10, acc[4]); acc[5] = fmaf(w12, x11, acc[5]);
        acc[6] = fmaf(w13, x10, acc[6]); acc[7] = fmaf(w13, x11, acc[7]);
    }
    if (i < deg) {
        int e0 = o0 + i;
        int s0 = csr[e0];
        float4 as0 = *reinterpret_cast<const float4*>(a_s1 + (size_t)s0 * 4);
        unsigned u0 = *reinterpret_cast<const unsigned*>(x_bf + (size_t)s0 * 128 + lane * 2);
        float w00 = __expf(lrelu(as0.x + ad.x)), w01 = __expf(lrelu(as0.y + ad.y));
        float w02 = __expf(lrelu(as0.z + ad.z)), w03 = __expf(lrelu(as0.w + ad.w));
        sm0 += w00; sm1 += w01; sm2 += w02; sm3 += w03;
        float x00 = bf2f((unsigned short)(u0 & 0xffff)), x01 = bf2f((unsigned short)(u0 >> 16));
        acc[0] = fmaf(w00, x00, acc[0]); acc[1] = fmaf(w00, x01, acc[1]);
        acc[2] = fmaf(w01, x00, acc[2]); acc[3] = fmaf(w01, x01, acc[3]);
        acc[4] = fmaf(w02, x00, acc[4]); acc[5] = fmaf(w02, x01, acc[5]);
        acc[6] = fmaf(w03, x00, acc[6]); acc[7] = fmaf(w03, x01, acc[7]);
    }
    float inv[4] = {1.f / sm0, 1.f / sm1, 1.f / sm2, 1.f / sm3};
#pragma unroll
    for (int h = 0; h < 4; ++h) {
        unsigned o = (unsigned)f2bf(acc[h * 2] * inv[h]) |
                     ((unsigned)f2bf(acc[h * 2 + 1] * inv[h]) << 16);
        *reinterpret_cast<unsigned*>(z + (size_t)h * Mpad * 128 + zoff) = o;
    }
}

// ------------------------------------------------------------------
// gather2_f: fused softmax+gather layer 2 (H=1), XCD-pinned 2 panels,
// + fused mean into 32-way REPLICATED accumulators (spread contention:
// ~78 atomics/address instead of 2500). No h2 materialization.
// ------------------------------------------------------------------
__global__ __launch_bounds__(256) void gather2_f(const unsigned short* __restrict__ xl,
                                                 const float* __restrict__ a_s,
                                                 const float* __restrict__ a_d,
                                                 const int* __restrict__ offsets,
                                                 const int* __restrict__ csr_src,
                                                 const float* __restrict__ bias,
                                                 float* __restrict__ meanv_rep, int N)
{
    const int panel = blockIdx.x & 1;
    const int dstq = blockIdx.x >> 1;
    const int wid = threadIdx.x >> 6;
    const int lane = threadIdx.x & 63;
    const int dst = dstq * 4 + wid;
    const bool valid = dst < N;
    const int g = lane >> 4;
    const int cb = panel * 128 + (lane & 15) * 8;

    __shared__ float psum[128];
    if (threadIdx.x < 128) psum[threadIdx.x] = 0.f;
    __syncthreads();

    float r[8];
#pragma unroll
    for (int k = 0; k < 8; ++k) r[k] = 0.f;

    if (valid) {
        const float ad = a_d[dst];
        const int o0 = offsets[dst];
        const int deg = offsets[dst + 1] - o0;

        float acc[8];
#pragma unroll
        for (int k = 0; k < 8; ++k) acc[k] = 0.f;
        float ssum = 0.f;

        int i = g;
        for (; i + 4 < deg; i += 8) {
            int e0 = o0 + i, e1 = e0 + 4;
            int s0 = csr_src[e0], s1 = csr_src[e1];
            float w0 = __expf(lrelu(a_s[s0] + ad));
            float w1 = __expf(lrelu(a_s[s1] + ad));
            ssum += w0 + w1;
            short8 v0 = *reinterpret_cast<const short8*>(xl + (size_t)s0 * 256 + cb);
            short8 v1 = *reinterpret_cast<const short8*>(xl + (size_t)s1 * 256 + cb);
#pragma unroll
            for (int k = 0; k < 8; ++k) {
                acc[k] = fmaf(w0, bf2f((unsigned short)v0[k]), acc[k]);
                acc[k] = fmaf(w1, bf2f((unsigned short)v1[k]), acc[k]);
            }
        }
        for (; i < deg; i += 4) {
            int e = o0 + i;
            int s = csr_src[e];
            float w = __expf(lrelu(a_s[s] + ad));
            ssum += w;
            short8 v = *reinterpret_cast<const short8*>(xl + (size_t)s * 256 + cb);
#pragma unroll
            for (int k = 0; k < 8; ++k)
                acc[k] = fmaf(w, bf2f((unsigned short)v[k]), acc[k]);
        }
        ssum += __shfl_xor(ssum, 16);
        ssum += __shfl_xor(ssum, 32);
#pragma unroll
        for (int k = 0; k < 8; ++k) {
            acc[k] += __shfl_xor(acc[k], 16);
            acc[k] += __shfl_xor(acc[k], 32);
        }
        if (lane < 16) {
            const float inv = 1.f / ssum;
            float4 b0 = *reinterpret_cast<const float4*>(bias + cb);
            float4 b1 = *reinterpret_cast<const float4*>(bias + cb + 4);
            r[0] = fmaxf(acc[0] * inv + b0.x, 0.f); r[1] = fmaxf(acc[1] * inv + b0.y, 0.f);
            r[2] = fmaxf(acc[2] * inv + b0.z, 0.f); r[3] = fmaxf(acc[3] * inv + b0.w, 0.f);
            r[4] = fmaxf(acc[4] * inv + b1.x, 0.f); r[5] = fmaxf(acc[5] * inv + b1.y, 0.f);
            r[6] = fmaxf(acc[6] * inv + b1.z, 0.f); r[7] = fmaxf(acc[7] * inv + b1.w, 0.f);
        }
    }

    if (valid && lane < 16) {
        const int lc = (lane & 15) * 8;
#pragma unroll
        for (int k = 0; k < 8; ++k)
            atomicAdd(&psum[lc + k], r[k]);
    }
    __syncthreads();
    if (threadIdx.x < 128)
        atomicAdd(&meanv_rep[(size_t)(dstq & 31) * 256 + panel * 128 + threadIdx.x],
                  psum[threadIdx.x]);
}

// ------------------------------------------------------------------
// final_k: sum 32 replicas -> mean -> tiny classifier GEMV. 256 threads.
// ------------------------------------------------------------------
__global__ __launch_bounds__(256) void final_k(const float* __restrict__ meanv_rep,
                                               const float* __restrict__ Wc,
                                               const float* __restrict__ bc,
                                               float* __restrict__ out, int N, int NCLS)
{
    __shared__ float mv[256];
    const int t = threadIdx.x;
    float s = 0.f;
#pragma unroll
    for (int rep = 0; rep < 32; ++rep)
        s += meanv_rep[(size_t)rep * 256 + t];
    mv[t] = s / (float)N;
    __syncthreads();
    if (t < NCLS) {
        float acc = bc[t];
        for (int c = 0; c < 256; ++c)
            acc = fmaf(mv[c], Wc[c * NCLS + t], acc);
        out[t] = acc;
    }
}

// ------------------------------------------------------------------
extern "C" void kernel_launch(void* const* d_in, const int* in_sizes, int n_in,
                              void* d_out, int out_size, void* d_ws, size_t ws_size,
                              hipStream_t stream)
{
    const float* x   = (const float*)d_in[0];
    const int*   ei  = (const int*)d_in[1];
    const float* W1  = (const float*)d_in[2];
    const float* as1 = (const float*)d_in[3];
    const float* ad1 = (const float*)d_in[4];
    const float* b1  = (const float*)d_in[5];
    const float* W2  = (const float*)d_in[6];
    const float* as2 = (const float*)d_in[7];
    const float* ad2 = (const float*)d_in[8];
    const float* b2  = (const float*)d_in[9];
    const float* Wc  = (const float*)d_in[10];
    const float* bc  = (const float*)d_in[11];
    float* out = (float*)d_out;

    const int D = 128, H = 4, C = 256, HC = 1024;
    const int N = in_sizes[0] / D;              // 10000
    const int E = in_sizes[1] / 2;              // 160000
    const int E2 = E + N;
    const int NCLS = in_sizes[11];
    const int Mpad = ((N + 127) / 128) * 128;   // 10112
    const int NB_CONV = Mpad * D / 4 / 256;     // 1264
    const int NB_E = (E2 + 255) / 256;          // 665

    char* ws = (char*)d_ws;
    size_t woff = 0;
    auto take = [&](size_t bytes) -> char* {
        char* p = ws + woff;
        woff += (bytes + 255) & ~(size_t)255;
        return p;
    };
    unsigned short* x_bf  = (unsigned short*)take((size_t)Mpad * D * 2);
    unsigned short* w1t   = (unsigned short*)take((size_t)HC * D * 2);
    unsigned short* w2t   = (unsigned short*)take((size_t)C * HC * 2);
    unsigned short* z     = (unsigned short*)take((size_t)4 * Mpad * 128 * 2);
    unsigned short* h1    = (unsigned short*)take((size_t)Mpad * HC * 2);
    unsigned short* xl2   = (unsigned short*)take((size_t)Mpad * C * 2);
    float* watt   = (float*)take(1024 * 4);
    float* a_s1   = (float*)take((size_t)N * H * 4);
    float* a_d1   = (float*)take((size_t)N * H * 4);
    int*   offs   = (int*)take((size_t)(N + 1) * 4);
    int*   csrsrc = (int*)take((size_t)E2 * 4);
    // ---- contiguous zero-init region (single memset) ----
    char* zero_base = ws + woff;
    int*   counts = (int*)take((size_t)N * 4);
    int*   cursor = (int*)take((size_t)N * 4);
    float* a_s2   = (float*)take((size_t)Mpad * 4);   // atomic targets
    float* a_d2   = (float*)take((size_t)Mpad * 4);
    float* meanv_rep = (float*)take((size_t)32 * 256 * 4);
    size_t zero_bytes = (size_t)((ws + woff) - zero_base);

    hipMemsetAsync(zero_base, 0, zero_bytes, stream);

    // prep + count_deg (fused)
    prep_all<<<NB_CONV + 128 + 256 + NB_E, 256, 0, stream>>>(
        x, x_bf, W1, w1t, W2, w2t, ei, counts, N * D / 4, NB_CONV, E, E2);

    // scan (block 0) + watt (blocks 1..8)
    scan_watt<<<9, 1024, 0, stream>>>(counts, offs, N, w1t, as1, ad1, watt);

    // scatter + score1 (fused)
    scatter_score<<<NB_E + (N + 3) / 4, 256, 0, stream>>>(
        ei, E, E2, offs, cursor, csrsrc, NB_E, x_bf, watt, a_s1, a_d1, N);

    // Layer 1: fused softmax-gather on x, then block-diag GEMM
    zgather_f<<<(Mpad + 3) / 4, 256, 0, stream>>>(x_bf, a_s1, a_d1, offs, csrsrc, z, N, Mpad);
    gemm_bf16<<<dim3(2, Mpad / 128, 4), 256, 0, stream>>>(
        z, 128, (size_t)Mpad * 128, w1t, 128, (size_t)256 * 128,
        h1, 1024, 256, b1, 1, 128);

    // Layer 2: GEMM (+fused attn scores) then fused softmax-gather+mean
    gemm_n64<<<dim3(C / 64, Mpad / 64), 256, 0, stream>>>(
        h1, 1024, w2t, 1024, xl2, 256, 1024, as2, ad2, a_s2, a_d2);
    gather2_f<<<((N + 3) / 4) * 2, 256, 0, stream>>>(xl2, a_s2, a_d2, offs, csrsrc, b2,
                                                     meanv_rep, N);

    // Classifier (sums replicas)
    final_k<<<1, 256, 0, stream>>>(meanv_rep, Wc, bc, out, N, NCLS);
}